// Round 3
// baseline (448.263 us; speedup 1.0000x reference)
//
#include <hip/hip_runtime.h>
#include <hip/hip_bf16.h>

// Problem constants
#define B_    8
#define T_    4096
#define D_    1024
#define S_    64
#define NQ_   8
#define QDIM_ 256
#define TB_   64            // t-rows per partial-sum block
#define NTC_  (T_/TB_)      // 64 chunks

typedef __attribute__((ext_vector_type(4))) unsigned short u16x4;
typedef __attribute__((ext_vector_type(8))) unsigned short u16x8;
typedef __attribute__((ext_vector_type(4))) float f32x4;

__device__ __forceinline__ float b2f(unsigned short u) {
    union { unsigned int i; float f; } v; v.i = ((unsigned int)u) << 16; return v.f;
}
__device__ __forceinline__ unsigned short f2b(float f) {
    __hip_bfloat16 h = __float2bfloat16(f);   // RNE
    return *reinterpret_cast<unsigned short*>(&h);
}

// dtype-parameterized scalar load
template<bool F32>
__device__ __forceinline__ float LD(const void* p, size_t i) {
    if constexpr (F32) return ((const float*)p)[i];
    else               return b2f(((const unsigned short*)p)[i]);
}

// LDS-tree block reductions, 256 threads, buf is 256-float scratch.
__device__ __forceinline__ float blockSum(float v, float* buf) {
    int tid = threadIdx.x;
    buf[tid] = v; __syncthreads();
    #pragma unroll
    for (int s = 128; s > 0; s >>= 1) { if (tid < s) buf[tid] += buf[tid + s]; __syncthreads(); }
    float r = buf[0]; __syncthreads();
    return r;
}
__device__ __forceinline__ float blockMax(float v, float* buf) {
    int tid = threadIdx.x;
    buf[tid] = v; __syncthreads();
    #pragma unroll
    for (int s = 128; s > 0; s >>= 1) { if (tid < s) buf[tid] = fmaxf(buf[tid], buf[tid + s]); __syncthreads(); }
    float r = buf[0]; __syncthreads();
    return r;
}

// K0: dtype detection. Reads first 256 u16 of x and Wq. bf16 buffers -> ~256
// plausible decodes; f32 buffers -> ~143 (only odd/high-half u16s plausible).
__global__ void k_detect(const unsigned short* __restrict__ x,
                         const unsigned short* __restrict__ wq,
                         int* __restrict__ flags) {
    if (threadIdx.x == 0 && blockIdx.x == 0) {
        int cx = 0, cw = 0;
        for (int i = 0; i < 256; ++i) {
            unsigned short u = x[i];
            unsigned e = (u >> 7) & 0xFF;
            if ((u & 0x7FFF) == 0 || (e >= 100 && e <= 130)) cx++;   // |v| in [2^-27, 16) for N(0,1)
            u = wq[i];
            e = (u >> 7) & 0xFF;
            if ((u & 0x7FFF) == 0 || (e >= 96 && e <= 126)) cw++;    // |v| in [2^-31, 0.5) for 0.02*N
        }
        flags[0] = (cx < 200) ? 1 : 0;   // 1 => x is f32
        flags[1] = (cw < 200) ? 1 : 0;   // 1 => weights are f32
    }
}

// K1: partial column sums of x. partials[tc][b][d] f32. grid = B_*NTC_, 256 thr.
__global__ __launch_bounds__(256)
void k_colsum(const void* __restrict__ x, float* __restrict__ partials,
              const int* __restrict__ flags) {
    int blk = blockIdx.x;
    int b  = blk >> 6;
    int tc = blk & 63;
    int tid = threadIdx.x;
    size_t base = ((size_t)(b * T_ + tc * TB_)) * D_ + tid * 4;
    float a0 = 0.f, a1 = 0.f, a2 = 0.f, a3 = 0.f;
    if (flags[0]) {
        const float* px = (const float*)x + base;
        #pragma unroll 8
        for (int i = 0; i < TB_; ++i) {
            f32x4 v = *reinterpret_cast<const f32x4*>(px + (size_t)i * D_);
            a0 += v[0]; a1 += v[1]; a2 += v[2]; a3 += v[3];
        }
    } else {
        const unsigned short* px = (const unsigned short*)x + base;
        #pragma unroll 8
        for (int i = 0; i < TB_; ++i) {
            u16x4 v = *reinterpret_cast<const u16x4*>(px + (size_t)i * D_);
            a0 += b2f(v[0]); a1 += b2f(v[1]); a2 += b2f(v[2]); a3 += b2f(v[3]);
        }
    }
    float* dst = partials + ((size_t)(tc * B_ + b)) * D_ + tid * 4;
    f32x4 r; r[0] = a0; r[1] = a1; r[2] = a2; r[3] = a3;
    *reinterpret_cast<f32x4*>(dst) = r;
}

// K2 body: per-slot core means -> feats[s][q]
template<bool F32>
__device__ void feats_body(const void* cf, const void* cm, const void* cl,
                           float* feats, float* buf) {
    int s = blockIdx.x, tid = threadIdx.x;
    float out[8];
    float v = (tid < 64) ? LD<F32>(cf, (size_t)s * 64 + tid) : 0.f;
    out[0] = blockSum(v, buf) * (1.f / 64.f);
    for (int j = 0; j < 6; ++j) {
        size_t base = ((size_t)(s * 6 + j)) * 2048;
        float a = 0.f;
        for (int k = tid; k < 2048; k += 256) a += LD<F32>(cm, base + k);
        out[1 + j] = blockSum(a, buf) * (1.f / 2048.f);
    }
    float w = (tid < 64) ? LD<F32>(cl, (size_t)s * 64 + tid) : 0.f;
    out[7] = blockSum(w, buf) * (1.f / 64.f);
    if (tid == 0) {
        #pragma unroll
        for (int q = 0; q < 8; ++q) feats[s * 8 + q] = out[q];
    }
}

__global__ __launch_bounds__(256)
void k_feats(const void* cf, const void* cm, const void* cl,
             float* feats, const int* flags) {
    __shared__ float buf[256];
    if (flags[1]) feats_body<true>(cf, cm, cl, feats, buf);
    else          feats_body<false>(cf, cm, cl, feats, buf);
}

// K3 shared state
struct MidSmem {
    float xs[D_];
    float qa[QDIM_];
    float sm0[NQ_], sm1[NQ_];
    float resA[S_ * 33];
    float resB[S_ * 33];
    float pov[S_ * 4];
    float att[S_];
    float gl[NQ_];
    float buf[256];
};

template<bool F32>
__device__ void middle_body(const float* __restrict__ partials,
                            const void* Wq, const void* bq,
                            const void* cf, const void* cm, const void* cl,
                            const void* Wd, const void* bd,
                            const float* __restrict__ feats,
                            float* __restrict__ read_proj,
                            MidSmem& sm) {
    int b = blockIdx.x, tid = threadIdx.x;

    // 1) finish column mean
    {
        int d0 = tid * 4;
        f32x4 acc; acc[0] = acc[1] = acc[2] = acc[3] = 0.f;
        for (int tc = 0; tc < NTC_; ++tc) {
            f32x4 p = *reinterpret_cast<const f32x4*>(partials + ((size_t)(tc * B_ + b)) * D_ + d0);
            acc += p;
        }
        const float sc = 1.f / (float)T_;
        sm.xs[d0 + 0] = acc[0] * sc; sm.xs[d0 + 1] = acc[1] * sc;
        sm.xs[d0 + 2] = acc[2] * sc; sm.xs[d0 + 3] = acc[3] * sc;
    }
    __syncthreads();

    // 2) logits (j = tid), softmax over 256
    {
        float lg = LD<F32>(bq, tid);
        #pragma unroll 8
        for (int d = 0; d < D_; ++d) lg += sm.xs[d] * LD<F32>(Wq, (size_t)d * QDIM_ + tid);
        float mx = blockMax(lg, sm.buf);
        float e = __expf(lg - mx);
        float ss = blockSum(e, sm.buf);
        sm.qa[tid] = e / ss;
    }
    __syncthreads();

    // 3) amp means with JAX clamped OOB gather
    if (tid < 16) {
        int q = tid >> 1, bit = tid & 1;
        int sw = 1 << (7 - q);
        float acc = 0.f;
        for (int i = 0; i < sw; ++i) {
            int idx = 2 * sw * i + bit * sw;
            if (idx > QDIM_ - 1) idx = QDIM_ - 1;
            acc += sm.qa[idx];
        }
        if (bit == 0) sm.sm0[q] = acc / (float)sw; else sm.sm1[q] = acc / (float)sw;
    }
    __syncthreads();

    // 4) MPS contraction: 4 threads/slot, each owns 8 of 32 bond components
    int sl = tid >> 2;
    int tq = tid & 3;
    int r0 = tq * 8;
    {
        float m0 = sm.sm0[0], m1 = sm.sm1[0];
        #pragma unroll
        for (int k = 0; k < 8; ++k) {
            float c0 = LD<F32>(cf, (size_t)sl * 64 + r0 + k);
            float c1 = LD<F32>(cf, (size_t)sl * 64 + 32 + r0 + k);
            sm.resA[sl * 33 + r0 + k] = m0 * c0 + m1 * c1;
        }
    }
    __syncthreads();
    float* cur = sm.resA; float* nxt = sm.resB;
    for (int q = 1; q <= 6; ++q) {
        float m0 = sm.sm0[q], m1 = sm.sm1[q];
        size_t base = ((size_t)(sl * 6 + (q - 1))) * 2048 + r0;
        float acc[8];
        #pragma unroll
        for (int k = 0; k < 8; ++k) acc[k] = 0.f;
        for (int l = 0; l < 32; ++l) {
            float rl = cur[sl * 33 + l];
            #pragma unroll
            for (int k = 0; k < 8; ++k) {
                float c0 = LD<F32>(cm, base + l * 64 + k);
                float c1 = LD<F32>(cm, base + l * 64 + 32 + k);
                acc[k] += rl * (m0 * c0 + m1 * c1);
            }
        }
        #pragma unroll
        for (int k = 0; k < 8; ++k) nxt[sl * 33 + r0 + k] = acc[k];
        __syncthreads();
        float* t = cur; cur = nxt; nxt = t;
    }

    // 5) overlap with last core (layout [S][32][2])
    {
        float m0 = sm.sm0[7], m1 = sm.sm1[7];
        float p = 0.f;
        #pragma unroll
        for (int k = 0; k < 8; ++k) {
            int l = r0 + k;
            float w0 = LD<F32>(cl, (size_t)sl * 64 + l * 2 + 0);
            float w1 = LD<F32>(cl, (size_t)sl * 64 + l * 2 + 1);
            p += cur[sl * 33 + l] * (m0 * w0 + m1 * w1);
        }
        sm.pov[sl * 4 + tq] = p;
    }
    __syncthreads();

    // 6) attention softmax over 64 slots (wave 0, shuffles only)
    if (tid < 64) {
        float o = sm.pov[tid * 4] + sm.pov[tid * 4 + 1] + sm.pov[tid * 4 + 2] + sm.pov[tid * 4 + 3];
        float mx = o;
        #pragma unroll
        for (int off = 32; off > 0; off >>= 1) mx = fmaxf(mx, __shfl_xor(mx, off, 64));
        float e = __expf(o - mx);
        float se = e;
        #pragma unroll
        for (int off = 32; off > 0; off >>= 1) se += __shfl_xor(se, off, 64);
        sm.att[tid] = e / se;
    }
    __syncthreads();

    // 7) g[q] = sum_s att[s] * feats[s][q]
    if (tid < 8) {
        float g = 0.f;
        for (int s2 = 0; s2 < S_; ++s2) g += sm.att[s2] * feats[s2 * 8 + tid];
        sm.gl[tid] = g;
    }
    __syncthreads();

    // 8) read_proj[b,d] = bd[d] + sum_c g[c&7] * Wd[c,d]
    {
        int d0 = tid * 4;
        float a0 = LD<F32>(bd, d0 + 0), a1 = LD<F32>(bd, d0 + 1);
        float a2 = LD<F32>(bd, d0 + 2), a3 = LD<F32>(bd, d0 + 3);
        for (int c = 0; c < QDIM_; ++c) {
            float gv = sm.gl[c & 7];
            size_t wb = (size_t)c * D_ + d0;
            a0 += gv * LD<F32>(Wd, wb + 0); a1 += gv * LD<F32>(Wd, wb + 1);
            a2 += gv * LD<F32>(Wd, wb + 2); a3 += gv * LD<F32>(Wd, wb + 3);
        }
        f32x4 r; r[0] = a0; r[1] = a1; r[2] = a2; r[3] = a3;
        *reinterpret_cast<f32x4*>(read_proj + (size_t)b * D_ + d0) = r;
    }
}

__global__ __launch_bounds__(256)
void k_middle(const float* partials,
              const void* Wq, const void* bq,
              const void* cf, const void* cm, const void* cl,
              const void* Wd, const void* bd,
              const float* feats, float* read_proj, const int* flags) {
    __shared__ MidSmem sm;
    if (flags[1]) middle_body<true>(partials, Wq, bq, cf, cm, cl, Wd, bd, feats, read_proj, sm);
    else          middle_body<false>(partials, Wq, bq, cf, cm, cl, Wd, bd, feats, read_proj, sm);
}

// K4: out = x + read_proj[b,:] broadcast. Output dtype FOLLOWS x's dtype
// (reference returns x + proj, same dtype as x). 8 elems/lane.
__global__ __launch_bounds__(256)
void k_add(const void* __restrict__ x, const float* __restrict__ rp,
           void* __restrict__ out, const int* __restrict__ flags) {
    size_t base = (((size_t)blockIdx.x) * 256 + threadIdx.x) * 8;
    int b = (int)(base >> 22);          // T_*D_ = 2^22
    int d = (int)(base & (D_ - 1));
    const float* r = rp + (size_t)b * D_ + d;
    f32x4 r0 = *reinterpret_cast<const f32x4*>(r);
    f32x4 r1 = *reinterpret_cast<const f32x4*>(r + 4);
    if (flags[0]) {
        // f32 in, f32 out
        const float* px = (const float*)x + base;
        f32x4 v0 = *reinterpret_cast<const f32x4*>(px);
        f32x4 v1 = *reinterpret_cast<const f32x4*>(px + 4);
        f32x4 o0 = v0 + r0;
        f32x4 o1 = v1 + r1;
        float* po = (float*)out + base;
        *reinterpret_cast<f32x4*>(po) = o0;
        *reinterpret_cast<f32x4*>(po + 4) = o1;
    } else {
        // bf16 in, bf16 out
        u16x8 v = *reinterpret_cast<const u16x8*>((const unsigned short*)x + base);
        u16x8 o;
        #pragma unroll
        for (int k = 0; k < 4; ++k) o[k] = f2b(b2f(v[k]) + r0[k]);
        #pragma unroll
        for (int k = 0; k < 4; ++k) o[4 + k] = f2b(b2f(v[4 + k]) + r1[k]);
        *reinterpret_cast<u16x8*>((unsigned short*)out + base) = o;
    }
}

extern "C" void kernel_launch(void* const* d_in, const int* in_sizes, int n_in,
                              void* d_out, int out_size, void* d_ws, size_t ws_size,
                              hipStream_t stream) {
    const void* x  = d_in[0];
    const void* Wq = d_in[1];
    const void* bq = d_in[2];
    const void* Wd = d_in[3];
    const void* bd = d_in[4];
    const void* cf = d_in[5];
    const void* cm = d_in[6];
    const void* cl = d_in[7];

    float* ws        = (float*)d_ws;
    float* partials  = ws;                                   // 524288 f32 (2 MB)
    float* feats     = partials + (size_t)NTC_ * B_ * D_;    // 512 f32
    float* read_proj = feats + S_ * NQ_;                     // 8192 f32
    int*   flags     = (int*)(read_proj + B_ * D_);          // 2 ints

    k_detect<<<1, 64, 0, stream>>>((const unsigned short*)x, (const unsigned short*)Wq, flags);
    k_colsum<<<B_ * NTC_, 256, 0, stream>>>(x, partials, flags);
    k_feats<<<S_, 256, 0, stream>>>(cf, cm, cl, feats, flags);
    k_middle<<<B_, 256, 0, stream>>>(partials, Wq, bq, cf, cm, cl, Wd, bd, feats, read_proj, flags);
    k_add<<<(B_ * T_ * D_) / 2048, 256, 0, stream>>>(x, read_proj, d_out, flags);
}

// Round 4
// 316.916 us; speedup vs baseline: 1.4145x; 1.4145x over previous
//
#include <hip/hip_runtime.h>
#include <hip/hip_bf16.h>

// Problem constants
#define B_    8
#define T_    4096
#define D_    1024
#define S_    64
#define NQ_   8
#define QDIM_ 256
#define TB_   64            // t-rows per partial-sum block
#define NTC_  (T_/TB_)      // 64 chunks

typedef __attribute__((ext_vector_type(4))) unsigned short u16x4;
typedef __attribute__((ext_vector_type(8))) unsigned short u16x8;
typedef __attribute__((ext_vector_type(4))) float f32x4;

__device__ __forceinline__ float b2f(unsigned short u) {
    union { unsigned int i; float f; } v; v.i = ((unsigned int)u) << 16; return v.f;
}
__device__ __forceinline__ unsigned short f2b(float f) {
    __hip_bfloat16 h = __float2bfloat16(f);   // RNE
    return *reinterpret_cast<unsigned short*>(&h);
}

// LDS-tree block reductions, 256 threads, buf is 256-float scratch.
__device__ __forceinline__ float blockSum(float v, float* buf) {
    int tid = threadIdx.x;
    buf[tid] = v; __syncthreads();
    #pragma unroll
    for (int s = 128; s > 0; s >>= 1) { if (tid < s) buf[tid] += buf[tid + s]; __syncthreads(); }
    float r = buf[0]; __syncthreads();
    return r;
}
__device__ __forceinline__ float blockMax(float v, float* buf) {
    int tid = threadIdx.x;
    buf[tid] = v; __syncthreads();
    #pragma unroll
    for (int s = 128; s > 0; s >>= 1) { if (tid < s) buf[tid] = fmaxf(buf[tid], buf[tid + s]); __syncthreads(); }
    float r = buf[0]; __syncthreads();
    return r;
}

// K0: dtype detection, parallel (256 threads, ballot+popcount).
// bf16 buffers -> ~256/256 plausible u16 decodes; f32 -> ~143/256.
__global__ __launch_bounds__(256)
void k_detect(const unsigned short* __restrict__ x,
              const unsigned short* __restrict__ wq,
              int* __restrict__ flags) {
    __shared__ int cnt[2];
    int tid = threadIdx.x;
    if (tid == 0) { cnt[0] = 0; cnt[1] = 0; }
    __syncthreads();
    unsigned short u = x[tid];
    unsigned e = (u >> 7) & 0xFF;
    bool okx = ((u & 0x7FFF) == 0) || (e >= 100 && e <= 130);   // |v| in [2^-27,16)
    u = wq[tid];
    e = (u >> 7) & 0xFF;
    bool okw = ((u & 0x7FFF) == 0) || (e >= 96 && e <= 126);    // |v| in [2^-31,0.5)
    unsigned long long bx = __ballot(okx);
    unsigned long long bw = __ballot(okw);
    if ((tid & 63) == 0) {
        atomicAdd(&cnt[0], (int)__popcll(bx));
        atomicAdd(&cnt[1], (int)__popcll(bw));
    }
    __syncthreads();
    if (tid == 0) {
        flags[0] = (cnt[0] < 200) ? 1 : 0;   // 1 => x is f32
        flags[1] = (cnt[1] < 200) ? 1 : 0;   // 1 => weights are f32
    }
}

// K1: partial column sums of x. partials[tc][b][d] f32. grid = B_*NTC_, 256 thr.
__global__ __launch_bounds__(256)
void k_colsum(const void* __restrict__ x, float* __restrict__ partials,
              const int* __restrict__ flags) {
    int blk = blockIdx.x;
    int b  = blk >> 6;
    int tc = blk & 63;
    int tid = threadIdx.x;
    size_t base = ((size_t)(b * T_ + tc * TB_)) * D_ + tid * 4;
    float a0 = 0.f, a1 = 0.f, a2 = 0.f, a3 = 0.f;
    if (flags[0]) {
        const float* px = (const float*)x + base;
        #pragma unroll 8
        for (int i = 0; i < TB_; ++i) {
            f32x4 v = *reinterpret_cast<const f32x4*>(px + (size_t)i * D_);
            a0 += v[0]; a1 += v[1]; a2 += v[2]; a3 += v[3];
        }
    } else {
        const unsigned short* px = (const unsigned short*)x + base;
        #pragma unroll 8
        for (int i = 0; i < TB_; ++i) {
            u16x4 v = *reinterpret_cast<const u16x4*>(px + (size_t)i * D_);
            a0 += b2f(v[0]); a1 += b2f(v[1]); a2 += b2f(v[2]); a3 += b2f(v[3]);
        }
    }
    float* dst = partials + ((size_t)(tc * B_ + b)) * D_ + tid * 4;
    f32x4 r; r[0] = a0; r[1] = a1; r[2] = a2; r[3] = a3;
    *reinterpret_cast<f32x4*>(dst) = r;
}

// K2: partial logits. grid = 64 (b*8+dc), 256 thr (j). Each block finishes
// its 128-wide xs chunk from partials, then 128-deep coalesced FMA loop.
__global__ __launch_bounds__(256)
void k_logits(const float* __restrict__ partials, const void* __restrict__ Wq,
              float* __restrict__ plog, const int* __restrict__ flags) {
    __shared__ float xs[128];
    int b = blockIdx.x >> 3, dc = blockIdx.x & 7;
    int tid = threadIdx.x;
    int d0 = dc * 128;
    if (tid < 128) {
        float a = 0.f;
        for (int tc = 0; tc < NTC_; ++tc)
            a += partials[((size_t)(tc * B_ + b)) * D_ + d0 + tid];
        xs[tid] = a * (1.f / (float)T_);
    }
    __syncthreads();
    float lg = 0.f;
    if (flags[1]) {
        const float* w = (const float*)Wq + (size_t)d0 * QDIM_ + tid;
        #pragma unroll 8
        for (int d = 0; d < 128; ++d) lg += xs[d] * w[(size_t)d * QDIM_];
    } else {
        const unsigned short* w = (const unsigned short*)Wq + (size_t)d0 * QDIM_ + tid;
        #pragma unroll 8
        for (int d = 0; d < 128; ++d) lg += xs[d] * b2f(w[(size_t)d * QDIM_]);
    }
    plog[((size_t)(b * 8 + dc)) * QDIM_ + tid] = lg;
}

// K3: combine partial logits + bq, softmax, clamped amp-means. grid = 8 (b).
__global__ __launch_bounds__(256)
void k_softmax_amp(const float* __restrict__ plog, const void* __restrict__ bq,
                   float* __restrict__ sm0m, float* __restrict__ sm1m,
                   const int* __restrict__ flags) {
    __shared__ float qa[QDIM_];
    __shared__ float buf[256];
    int b = blockIdx.x, tid = threadIdx.x;
    float lg = flags[1] ? ((const float*)bq)[tid] : b2f(((const unsigned short*)bq)[tid]);
    for (int dc = 0; dc < 8; ++dc) lg += plog[((size_t)(b * 8 + dc)) * QDIM_ + tid];
    float mx = blockMax(lg, buf);
    float e = __expf(lg - mx);
    float ss = blockSum(e, buf);
    qa[tid] = e / ss;
    __syncthreads();
    // amp means with JAX clamped OOB gather
    if (tid < 16) {
        int q = tid >> 1, bit = tid & 1;
        int sw = 1 << (7 - q);
        float acc = 0.f;
        for (int i = 0; i < sw; ++i) {
            int idx = 2 * sw * i + bit * sw;
            if (idx > QDIM_ - 1) idx = QDIM_ - 1;
            acc += qa[idx];
        }
        float m = acc / (float)sw;
        if (bit == 0) sm0m[b * 8 + q] = m; else sm1m[b * 8 + q] = m;
    }
}

// K4: MPS contraction + feats. grid = 64 (one block per slot s), 256 thr
// (b = tid>>5, r = tid&31). Slot cores staged once to LDS, all 8 batches
// computed from LDS. Also emits feats[s][8] (cores already on-chip).
__global__ __launch_bounds__(256)
void k_mps(const void* __restrict__ cf, const void* __restrict__ cm,
           const void* __restrict__ cl,
           const float* __restrict__ sm0m, const float* __restrict__ sm1m,
           float* __restrict__ feats, float* __restrict__ ovl,
           const int* __restrict__ flags) {
    __shared__ float lcf[64];
    __shared__ float lcm[6 * 2048];     // [j][l][p][r] as in global
    __shared__ float lcl[64];           // [r][p]
    __shared__ float res[8][33];
    __shared__ float nres[8][33];
    __shared__ float buf[256];
    __shared__ float lm0[64], lm1[64];
    int s = blockIdx.x, tid = threadIdx.x;
    if (flags[1]) {
        const float* pcm = (const float*)cm + (size_t)s * 12288;
        for (int i = tid; i < 12288; i += 256) lcm[i] = pcm[i];
        if (tid < 64) {
            lcf[tid] = ((const float*)cf)[s * 64 + tid];
            lcl[tid] = ((const float*)cl)[s * 64 + tid];
        }
    } else {
        const unsigned short* pcm = (const unsigned short*)cm + (size_t)s * 12288;
        for (int i = tid; i < 12288; i += 256) lcm[i] = b2f(pcm[i]);
        if (tid < 64) {
            lcf[tid] = b2f(((const unsigned short*)cf)[s * 64 + tid]);
            lcl[tid] = b2f(((const unsigned short*)cl)[s * 64 + tid]);
        }
    }
    if (tid < 64) { lm0[tid] = sm0m[tid]; lm1[tid] = sm1m[tid]; }
    __syncthreads();

    // feats from LDS
    {
        float v = (tid < 64) ? lcf[tid] : 0.f;
        float f0 = blockSum(v, buf) * (1.f / 64.f);
        float fj[6];
        for (int j = 0; j < 6; ++j) {
            float a = 0.f;
            for (int k = tid; k < 2048; k += 256) a += lcm[j * 2048 + k];
            fj[j] = blockSum(a, buf) * (1.f / 2048.f);
        }
        float w = (tid < 64) ? lcl[tid] : 0.f;
        float fl = blockSum(w, buf) * (1.f / 64.f);
        if (tid == 0) {
            feats[s * 8 + 0] = f0;
            #pragma unroll
            for (int j = 0; j < 6; ++j) feats[s * 8 + 1 + j] = fj[j];
            feats[s * 8 + 7] = fl;
        }
    }

    int b = tid >> 5, r = tid & 31;
    // q = 0: cf layout [2][32]
    res[b][r] = lm0[b * 8 + 0] * lcf[r] + lm1[b * 8 + 0] * lcf[32 + r];
    __syncthreads();
    for (int q = 1; q <= 6; ++q) {
        float m0 = lm0[b * 8 + q], m1 = lm1[b * 8 + q];
        const float* C = &lcm[(q - 1) * 2048];
        float acc = 0.f;
        #pragma unroll 8
        for (int l = 0; l < 32; ++l)
            acc += res[b][l] * (m0 * C[l * 64 + r] + m1 * C[l * 64 + 32 + r]);
        nres[b][r] = acc;
        __syncthreads();
        res[b][r] = nres[b][r];
        __syncthreads();
    }
    // overlap: cl layout [32][2]
    {
        float m0 = lm0[b * 8 + 7], m1 = lm1[b * 8 + 7];
        float p = res[b][r] * (m0 * lcl[r * 2] + m1 * lcl[r * 2 + 1]);
        #pragma unroll
        for (int off = 16; off > 0; off >>= 1) p += __shfl_xor(p, off, 64);
        if (r == 0) ovl[b * 64 + s] = p;
    }
}

// K5: attention softmax + g + read_proj. grid = 32 (b = >>2, dc = &3), 256 thr.
__global__ __launch_bounds__(256)
void k_attproj(const float* __restrict__ ovl, const float* __restrict__ feats,
               const void* __restrict__ Wd, const void* __restrict__ bd,
               float* __restrict__ read_proj, const int* __restrict__ flags) {
    __shared__ float att[S_];
    __shared__ float gl[NQ_];
    int b = blockIdx.x >> 2, dc = blockIdx.x & 3;
    int tid = threadIdx.x;
    if (tid < 64) {
        float o = ovl[b * 64 + tid];
        float mx = o;
        #pragma unroll
        for (int off = 32; off > 0; off >>= 1) mx = fmaxf(mx, __shfl_xor(mx, off, 64));
        float e = __expf(o - mx);
        float se = e;
        #pragma unroll
        for (int off = 32; off > 0; off >>= 1) se += __shfl_xor(se, off, 64);
        att[tid] = e / se;
    }
    __syncthreads();
    if (tid < 8) {
        float g = 0.f;
        for (int s2 = 0; s2 < S_; ++s2) g += att[s2] * feats[s2 * 8 + tid];
        gl[tid] = g;
    }
    __syncthreads();
    int d = dc * 256 + tid;
    float a = flags[1] ? ((const float*)bd)[d] : b2f(((const unsigned short*)bd)[d]);
    if (flags[1]) {
        const float* w = (const float*)Wd + d;
        #pragma unroll 8
        for (int c = 0; c < QDIM_; ++c) a += gl[c & 7] * w[(size_t)c * D_];
    } else {
        const unsigned short* w = (const unsigned short*)Wd + d;
        #pragma unroll 8
        for (int c = 0; c < QDIM_; ++c) a += gl[c & 7] * b2f(w[(size_t)c * D_]);
    }
    read_proj[(size_t)b * D_ + d] = a;
}

// K6: out = x + read_proj[b,:] broadcast. Output dtype follows x's dtype.
__global__ __launch_bounds__(256)
void k_add(const void* __restrict__ x, const float* __restrict__ rp,
           void* __restrict__ out, const int* __restrict__ flags) {
    size_t base = (((size_t)blockIdx.x) * 256 + threadIdx.x) * 8;
    int b = (int)(base >> 22);          // T_*D_ = 2^22
    int d = (int)(base & (D_ - 1));
    const float* r = rp + (size_t)b * D_ + d;
    f32x4 r0 = *reinterpret_cast<const f32x4*>(r);
    f32x4 r1 = *reinterpret_cast<const f32x4*>(r + 4);
    if (flags[0]) {
        const float* px = (const float*)x + base;
        f32x4 v0 = *reinterpret_cast<const f32x4*>(px);
        f32x4 v1 = *reinterpret_cast<const f32x4*>(px + 4);
        f32x4 o0 = v0 + r0;
        f32x4 o1 = v1 + r1;
        float* po = (float*)out + base;
        *reinterpret_cast<f32x4*>(po) = o0;
        *reinterpret_cast<f32x4*>(po + 4) = o1;
    } else {
        u16x8 v = *reinterpret_cast<const u16x8*>((const unsigned short*)x + base);
        u16x8 o;
        #pragma unroll
        for (int k = 0; k < 4; ++k) o[k] = f2b(b2f(v[k]) + r0[k]);
        #pragma unroll
        for (int k = 0; k < 4; ++k) o[4 + k] = f2b(b2f(v[4 + k]) + r1[k]);
        *reinterpret_cast<u16x8*>((unsigned short*)out + base) = o;
    }
}

extern "C" void kernel_launch(void* const* d_in, const int* in_sizes, int n_in,
                              void* d_out, int out_size, void* d_ws, size_t ws_size,
                              hipStream_t stream) {
    const void* x  = d_in[0];
    const void* Wq = d_in[1];
    const void* bq = d_in[2];
    const void* Wd = d_in[3];
    const void* bd = d_in[4];
    const void* cf = d_in[5];
    const void* cm = d_in[6];
    const void* cl = d_in[7];

    float* ws        = (float*)d_ws;
    float* partials  = ws;                        // 524288 f32 (2 MB)
    float* plog      = partials + 524288;         // 16384
    float* sm0m      = plog + 16384;              // 64
    float* sm1m      = sm0m + 64;                 // 64
    float* feats     = sm1m + 64;                 // 512
    float* ovl       = feats + 512;               // 512
    float* read_proj = ovl + 512;                 // 8192
    int*   flags     = (int*)(read_proj + 8192);  // 2 ints

    k_detect<<<1, 256, 0, stream>>>((const unsigned short*)x, (const unsigned short*)Wq, flags);
    k_colsum<<<B_ * NTC_, 256, 0, stream>>>(x, partials, flags);
    k_logits<<<64, 256, 0, stream>>>(partials, Wq, plog, flags);
    k_softmax_amp<<<B_, 256, 0, stream>>>(plog, bq, sm0m, sm1m, flags);
    k_mps<<<S_, 256, 0, stream>>>(cf, cm, cl, sm0m, sm1m, feats, ovl, flags);
    k_attproj<<<32, 256, 0, stream>>>(ovl, feats, Wd, bd, read_proj, flags);
    k_add<<<(B_ * T_ * D_) / 2048, 256, 0, stream>>>(x, read_proj, d_out, flags);
}